// Round 10
// baseline (222.264 us; speedup 1.0000x reference)
//
#include <hip/hip_runtime.h>
#include <hip/hip_bf16.h>
#include <math.h>

#define CUTOFFV 5.0f
#define NRAD 6
#define EMB 128
#define NTYPES 95
#define PI_F 3.14159265358979323846f

typedef short short8 __attribute__((ext_vector_type(8)));
typedef float f32x4 __attribute__((ext_vector_type(4)));
typedef float f32x2 __attribute__((ext_vector_type(2)));

__device__ __forceinline__ unsigned short f2bf(float f) {
    union { float f; unsigned int u; } v; v.f = f;
    unsigned int u = v.u;
    unsigned int r = (u + 0x7FFFu + ((u >> 16) & 1u)) >> 16;
    return (unsigned short)r;
}

__device__ __forceinline__ float fast_rcp(float x) {
    float y;
    asm("v_rcp_f32 %0, %1" : "=v"(y) : "v"(x));
    return y;
}

// silu via hardware rcp (1 ulp) instead of precise-division sequence
__device__ __forceinline__ float silu_f(float x) {
    return x * fast_rcp(1.0f + __expf(-x));
}

__device__ __forceinline__ float rdlane(float v, int l) {
    return __int_as_float(__builtin_amdgcn_readlane(__float_as_int(v), l));
}

// LDS-only barrier: waits ds ops (lgkmcnt) but does NOT drain vmcnt.
__device__ __forceinline__ void lds_barrier() {
    __builtin_amdgcn_sched_barrier(0);
    asm volatile("s_waitcnt lgkmcnt(0)\n\ts_barrier" ::: "memory");
    __builtin_amdgcn_sched_barrier(0);
}

// ---- prep: P1 = emb@W1^T + b_dense, P2 = emb@W2^T, W3 -> bf16, Wrp pack ----
__global__ void prep_kernel(const float* __restrict__ emb,
                            const float* __restrict__ Wd,
                            const float* __restrict__ bd,
                            const float* __restrict__ Wr,
                            const float* __restrict__ brbf,
                            float* __restrict__ P1, float* __restrict__ P2,
                            unsigned short* __restrict__ W3b,
                            float* __restrict__ Wrp) {
    int b = blockIdx.x, tid = threadIdx.x;
    if (b < 2 * NTYPES) {
        int t = b / NTYPES, z = b % NTYPES;
        __shared__ float emb_s[EMB];
        emb_s[tid] = emb[z * EMB + tid];
        __syncthreads();
        float acc = (t == 0) ? bd[tid] : 0.0f;
        const float* wrow = Wd + (size_t)tid * 384 + t * EMB;
        #pragma unroll 8
        for (int j = 0; j < EMB; ++j) acc += emb_s[j] * wrow[j];
        (t == 0 ? P1 : P2)[z * EMB + tid] = acc;
    } else if (b < 2 * NTYPES + 8) {
        int g = (b - 2 * NTYPES) * 128 + tid;   // 0..1023
        for (int i = g; i < EMB * EMB; i += 8 * 128) {
            int n = i >> 7, k = i & 127;
            W3b[i] = f2bf(Wd[(size_t)n * 384 + 256 + k]);
        }
    } else {
        // Wrp[k][8] = {w0..w5, bias, 0}
        if (tid < EMB) {
            int k = tid;
            #pragma unroll
            for (int j = 0; j < 6; ++j) Wrp[k * 8 + j] = Wr[k * 6 + j];
            Wrp[k * 8 + 6] = brbf[k];
            Wrp[k * 8 + 7] = 0.0f;
        }
    }
}

// ---------------- h output: gather rows of emb_table --------------------------
__global__ void h_kernel(const int* __restrict__ Z, const float* __restrict__ emb,
                         float* __restrict__ out_h, int N) {
    int idx = blockIdx.x * 256 + threadIdx.x;  // float4 index
    int total = N * (EMB / 4);
    if (idx >= total) return;
    int v = idx >> 5, c = idx & 31;            // 32 float4 per row
    int z = Z[v];
    const f32x4* e4 = (const f32x4*)emb;
    f32x4* o4 = (f32x4*)out_h;
    o4[idx] = e4[z * 32 + c];
}

// -- persistent edge kernel: software-pipelined, dbuf LDS, PLAIN stores --------
__global__ void __launch_bounds__(256, 4)
edge_kernel(const int* __restrict__ Z, const int* __restrict__ src,
            const int* __restrict__ dst, const float* __restrict__ rbf,
            const float* __restrict__ dvec,
            const float* __restrict__ P1, const float* __restrict__ P2,
            const unsigned short* __restrict__ W3b,
            const float* __restrict__ Wrp,
            float* __restrict__ out_m, float* __restrict__ out_env,
            int E, int ntiles) {
    __shared__ unsigned char A_lds[2][64 * 256]; // bf16 [edge][k], swizzled
    __shared__ int zs_s[2][64], zd_s[2][64];

    const int tid = threadIdx.x;
    const int lane = tid & 63;
    const int w = tid >> 6;          // wave id
    const int lr = lane & 15;
    const int lg = lane >> 4;

    // ---- per-block (loop-invariant) register caches ----
    const f32x4 cw = ((const f32x4*)Wrp)[tid];

    short8 wfrag[2][4];
    #pragma unroll
    for (int nt = 0; nt < 2; ++nt) {
        int n = w * 32 + nt * 16 + lr;
        #pragma unroll
        for (int ks = 0; ks < 4; ++ks)
            wfrag[nt][ks] = *(const short8*)(W3b + n * EMB + ks * 32 + lg * 8);
    }

    for (int i = 0; ; ++i) {
        const int tp = blockIdx.x + i * gridDim.x;   // tile to produce
        const int tc = tp - gridDim.x;               // tile to consume (prev it)
        const bool do_p = (tp < ntiles);
        const bool do_c = (i > 0) && (tc < ntiles);
        if (!do_p && !do_c) break;
        const int pi = i & 1, ci = pi ^ 1;

        // ---- A: issue produce-tile global loads (consumed after B) ----
        f32x2 ra = {0.f, 0.f}, rb = {0.f, 0.f}, rc = {0.f, 0.f};
        float dv = 0.0f;
        int srcv = 0, dstv = 0;
        if (do_p) {
            const int e0p = tp * 64;
            int ecl = e0p + lane; if (ecl >= E) ecl = E - 1;
            const f32x2* r2 = (const f32x2*)(rbf + (size_t)ecl * 6);
            ra = r2[0]; rb = r2[1]; rc = r2[2];
            if (tid < 64) {
                int ec = (e0p + tid < E) ? (e0p + tid) : (E - 1);
                srcv = src[ec]; dstv = dst[ec];
                dv = dvec[ec];
            }
        }

        // ---- B: consume tile tc (MFMA + epilogue; hides A's latency) ----
        if (do_c) {
            const int e0c = tc * 64;
            const unsigned char* Ab = A_lds[ci];
            #pragma unroll
            for (int et = 0; et < 4; ++et) {
                const int e_row = et * 16 + lr;
                short8 bfrag[4];
                #pragma unroll
                for (int ks = 0; ks < 4; ++ks) {
                    int off = (e_row * 256 + (ks * 32 + lg * 8) * 2) ^ ((e_row & 7) << 4);
                    bfrag[ks] = *(const short8*)(Ab + off);
                }
                f32x4 acc[2];
                acc[0] = (f32x4){0.f, 0.f, 0.f, 0.f};
                acc[1] = (f32x4){0.f, 0.f, 0.f, 0.f};
                #pragma unroll
                for (int ks = 0; ks < 4; ++ks)
                    #pragma unroll
                    for (int nt = 0; nt < 2; ++nt)
                        acc[nt] = __builtin_amdgcn_mfma_f32_16x16x32_bf16(
                            wfrag[nt][ks], bfrag[ks], acc[nt], 0, 0, 0);

                const int el = e_row;
                const int e = e0c + el;
                const int zs = zs_s[ci][el], zd = zd_s[ci][el];
                #pragma unroll
                for (int nt = 0; nt < 2; ++nt) {
                    int n4 = w * 32 + nt * 16 + lg * 4;
                    const f32x4 p1 = *(const f32x4*)(P1 + zs * EMB + n4);
                    const f32x4 p2 = *(const f32x4*)(P2 + zd * EMB + n4);
                    f32x4 o;
                    o.x = silu_f(acc[nt][0] + p1.x + p2.x);
                    o.y = silu_f(acc[nt][1] + p1.y + p2.y);
                    o.z = silu_f(acc[nt][2] + p1.z + p2.z);
                    o.w = silu_f(acc[nt][3] + p1.w + p2.w);
                    if (e < E)
                        *(f32x4*)(out_m + (size_t)e * EMB + n4) = o;  // plain
                }
            }
        }

        if (do_p) {
            const int e0p = tp * 64;

            // ---- C: env + issue Z gathers (latency hidden under D) ----
            int zsr = 0, zdr = 0;
            if (tid < 64) {
                zsr = Z[srcv]; zdr = Z[dstv];
                int e = e0p + tid;
                if (e < E) {
                    float x = dv * (1.0f / CUTOFFV);   // (0,1]
                    float inv = fast_rcp(x);
                    float x2 = x * x;
                    float x5 = x2 * x2 * x;
                    float env = inv + x5 * (-28.0f + x * (48.0f - 21.0f * x));
                    float s1, c1;
                    __sincosf(PI_F * x, &s1, &c1);
                    float twoc = 2.0f * c1;
                    float f = env * inv;
                    float s2 = twoc * s1;
                    float s3 = twoc * s2 - s1;
                    float s4 = twoc * s3 - s2;
                    float s5 = twoc * s4 - s3;
                    float s6 = twoc * s5 - s4;
                    float* o = out_env + (size_t)e * 6;
                    *(f32x2*)o       = (f32x2){f * s1, f * s2};   // plain
                    *(f32x2*)(o + 2) = (f32x2){f * s3, f * s4};
                    *(f32x2*)(o + 4) = (f32x2){f * s5, f * s6};
                }
            }

            // ---- D: producer (VALU-heavy): edge=lane, wave w -> k slice ----
            #pragma unroll
            for (int c = 0; c < 4; ++c) {
                short8 pk;
                #pragma unroll
                for (int j = 0; j < 8; ++j) {
                    const int ln = 2 * (c * 8 + j);     // compile-time constant
                    float w0 = rdlane(cw.x, ln),     w1 = rdlane(cw.y, ln);
                    float w2 = rdlane(cw.z, ln),     w3v = rdlane(cw.w, ln);
                    float w4 = rdlane(cw.x, ln + 1), w5 = rdlane(cw.y, ln + 1);
                    float bs = rdlane(cw.z, ln + 1);
                    float pre = bs + ra.x * w0 + ra.y * w1 + rb.x * w2 +
                                rb.y * w3v + rc.x * w4 + rc.y * w5;
                    pk[j] = (short)f2bf(silu_f(pre));
                }
                int k0 = w * 32 + c * 8;
                int off = (lane * 256 + k0 * 2) ^ ((lane & 7) << 4);
                *(short8*)(A_lds[pi] + off) = pk;
            }

            // ---- E: stash z indices for next iteration's consumer ----
            if (tid < 64) {
                zs_s[pi][tid] = zsr;
                zd_s[pi][tid] = zdr;
            }
        }

        lds_barrier();   // single barrier per tile; no vmcnt drain
    }
}

extern "C" void kernel_launch(void* const* d_in, const int* in_sizes, int n_in,
                              void* d_out, int out_size, void* d_ws, size_t ws_size,
                              hipStream_t stream) {
    const int* Z = (const int*)d_in[0];
    const int* src = (const int*)d_in[1];
    const int* dst = (const int*)d_in[2];
    const float* rbf = (const float*)d_in[3];
    const float* dvec = (const float*)d_in[4];
    const float* emb = (const float*)d_in[5];
    const float* Wr = (const float*)d_in[6];
    const float* brbf = (const float*)d_in[7];
    const float* Wd = (const float*)d_in[8];
    const float* bd = (const float*)d_in[9];

    const int N = in_sizes[0];
    const int E = in_sizes[1];

    float* out_h = (float*)d_out;
    float* out_m = out_h + (size_t)N * EMB;
    float* out_env = out_m + (size_t)E * EMB;

    // workspace: P1 | P2 (95*128 f32 each) | W3 bf16 (128*128) | Wrp (128*8 f32)
    float* P1 = (float*)d_ws;
    float* P2 = P1 + NTYPES * EMB;
    unsigned short* W3b = (unsigned short*)(P2 + NTYPES * EMB);
    float* Wrp = (float*)(W3b + EMB * EMB);

    prep_kernel<<<2 * NTYPES + 9, 128, 0, stream>>>(emb, Wd, bd, Wr, brbf,
                                                    P1, P2, W3b, Wrp);

    int hblocks = (N * (EMB / 4) + 255) / 256;
    h_kernel<<<hblocks, 256, 0, stream>>>(Z, emb, out_h, N);

    int ntiles = (E + 63) / 64;
    int grid = ntiles < 1024 ? ntiles : 1024;
    edge_kernel<<<grid, 256, 0, stream>>>(Z, src, dst, rbf, dvec,
                                          P1, P2, W3b, Wrp,
                                          out_m, out_env, E, ntiles);
}

// Round 11
// 164.266 us; speedup vs baseline: 1.3531x; 1.3531x over previous
//
#include <hip/hip_runtime.h>
#include <hip/hip_bf16.h>
#include <math.h>

#define CUTOFFV 5.0f
#define NRAD 6
#define EMB 128
#define NTYPES 95
#define PI_F 3.14159265358979323846f

typedef short short8 __attribute__((ext_vector_type(8)));
typedef float f32x4 __attribute__((ext_vector_type(4)));
typedef float f32x2 __attribute__((ext_vector_type(2)));

__device__ __forceinline__ unsigned short f2bf(float f) {
    union { float f; unsigned int u; } v; v.f = f;
    unsigned int u = v.u;
    unsigned int r = (u + 0x7FFFu + ((u >> 16) & 1u)) >> 16;
    return (unsigned short)r;
}

// compiler-lowered bf16 convert (RTNE, emits HW cvt)
__device__ __forceinline__ short bf16s(float f) {
    union { __hip_bfloat16 h; short s; } u;
    u.h = __float2bfloat16(f);
    return u.s;
}

__device__ __forceinline__ float fast_rcp(float x) {
    float y;
    asm("v_rcp_f32 %0, %1" : "=v"(y) : "v"(x));
    return y;
}

// silu via hardware rcp (1 ulp) instead of precise-division sequence
__device__ __forceinline__ float silu_f(float x) {
    return x * fast_rcp(1.0f + __expf(-x));
}

// LDS-only barrier: waits ds ops (lgkmcnt) but does NOT drain vmcnt.
__device__ __forceinline__ void lds_barrier() {
    __builtin_amdgcn_sched_barrier(0);
    asm volatile("s_waitcnt lgkmcnt(0)\n\ts_barrier" ::: "memory");
    __builtin_amdgcn_sched_barrier(0);
}

// ---- prep: P1 = emb@W1^T + b_dense, P2 = emb@W2^T, W3 -> bf16, Wrp pack ----
__global__ void prep_kernel(const float* __restrict__ emb,
                            const float* __restrict__ Wd,
                            const float* __restrict__ bd,
                            const float* __restrict__ Wr,
                            const float* __restrict__ brbf,
                            float* __restrict__ P1, float* __restrict__ P2,
                            unsigned short* __restrict__ W3b,
                            float* __restrict__ Wrp) {
    int b = blockIdx.x, tid = threadIdx.x;
    if (b < 2 * NTYPES) {
        int t = b / NTYPES, z = b % NTYPES;
        __shared__ float emb_s[EMB];
        emb_s[tid] = emb[z * EMB + tid];
        __syncthreads();
        float acc = (t == 0) ? bd[tid] : 0.0f;
        const float* wrow = Wd + (size_t)tid * 384 + t * EMB;
        #pragma unroll 8
        for (int j = 0; j < EMB; ++j) acc += emb_s[j] * wrow[j];
        (t == 0 ? P1 : P2)[z * EMB + tid] = acc;
    } else if (b < 2 * NTYPES + 8) {
        int g = (b - 2 * NTYPES) * 128 + tid;   // 0..1023
        for (int i = g; i < EMB * EMB; i += 8 * 128) {
            int n = i >> 7, k = i & 127;
            W3b[i] = f2bf(Wd[(size_t)n * 384 + 256 + k]);
        }
    } else {
        // Wrp[k][8] = {w0..w5, bias, 0}
        if (tid < EMB) {
            int k = tid;
            #pragma unroll
            for (int j = 0; j < 6; ++j) Wrp[k * 8 + j] = Wr[k * 6 + j];
            Wrp[k * 8 + 6] = brbf[k];
            Wrp[k * 8 + 7] = 0.0f;
        }
    }
}

// ---------------- h output: gather rows of emb_table --------------------------
__global__ void h_kernel(const int* __restrict__ Z, const float* __restrict__ emb,
                         float* __restrict__ out_h, int N) {
    int idx = blockIdx.x * 256 + threadIdx.x;  // float4 index
    int total = N * (EMB / 4);
    if (idx >= total) return;
    int v = idx >> 5, c = idx & 31;            // 32 float4 per row
    int z = Z[v];
    const f32x4* e4 = (const f32x4*)emb;
    f32x4* o4 = (f32x4*)out_h;
    o4[idx] = e4[z * 32 + c];
}

// ---------------- env: pure streaming (sincos + Chebyshev), nt stores ---------
__global__ void env_kernel(const float* __restrict__ dvec,
                           float* __restrict__ out_env, int E) {
    int e = blockIdx.x * 256 + threadIdx.x;
    if (e >= E) return;
    float x = dvec[e] * (1.0f / CUTOFFV);   // (0,1]
    float inv = fast_rcp(x);
    float x2 = x * x;
    float x5 = x2 * x2 * x;
    float env = inv + x5 * (-28.0f + x * (48.0f - 21.0f * x));
    float s1, c1;
    __sincosf(PI_F * x, &s1, &c1);
    float twoc = 2.0f * c1;
    float f = env * inv;
    float s2 = twoc * s1;
    float s3 = twoc * s2 - s1;
    float s4 = twoc * s3 - s2;
    float s5 = twoc * s4 - s3;
    float s6 = twoc * s5 - s4;
    float* o = out_env + (size_t)e * 6;
    __builtin_nontemporal_store((f32x2){f * s1, f * s2}, (f32x2*)o);
    __builtin_nontemporal_store((f32x2){f * s3, f * s4}, (f32x2*)(o + 2));
    __builtin_nontemporal_store((f32x2){f * s5, f * s6}, (f32x2*)(o + 4));
}

// -- persistent edge kernel: dbuf pipeline, s_load producer, NT stores ---------
__global__ void __launch_bounds__(256, 4)
edge_kernel(const int* __restrict__ Z, const int* __restrict__ src,
            const int* __restrict__ dst, const float* __restrict__ rbf,
            const float* __restrict__ P1, const float* __restrict__ P2,
            const unsigned short* __restrict__ W3b,
            const float* __restrict__ Wrp,
            float* __restrict__ out_m,
            int E, int ntiles) {
    __shared__ unsigned char A_lds[2][64 * 256]; // bf16 [edge][k], swizzled
    __shared__ int zs_s[2][64], zd_s[2][64];

    const int tid = threadIdx.x;
    const int lane = tid & 63;
    const int w = tid >> 6;          // wave id
    const int lr = lane & 15;
    const int lg = lane >> 4;
    const int wu = __builtin_amdgcn_readfirstlane(w);  // wave-uniform wave id

    // ---- per-block loop-invariant: W3 fragments (wave w owns n-slice) ----
    short8 wfrag[2][4];
    #pragma unroll
    for (int nt = 0; nt < 2; ++nt) {
        int n = w * 32 + nt * 16 + lr;
        #pragma unroll
        for (int ks = 0; ks < 4; ++ks)
            wfrag[nt][ks] = *(const short8*)(W3b + n * EMB + ks * 32 + lg * 8);
    }

    for (int i = 0; ; ++i) {
        const int tp = blockIdx.x + i * gridDim.x;   // tile to produce
        const int tc = tp - gridDim.x;               // tile to consume (prev it)
        const bool do_p = (tp < ntiles);
        const bool do_c = (i > 0) && (tc < ntiles);
        if (!do_p && !do_c) break;
        const int pi = i & 1, ci = pi ^ 1;

        // ---- A: issue produce-tile global loads (consumed after B) ----
        f32x2 ra = {0.f, 0.f}, rb = {0.f, 0.f}, rc = {0.f, 0.f};
        int iv = 0;
        if (do_p) {
            const int e0p = tp * 64;
            int ecl = e0p + lane; if (ecl >= E) ecl = E - 1;
            const f32x2* r2 = (const f32x2*)(rbf + (size_t)ecl * 6);
            ra = r2[0]; rb = r2[1]; rc = r2[2];
            if (tid < 128) {                         // waves 0,1: src / dst
                int ec = e0p + (tid & 63); if (ec >= E) ec = E - 1;
                iv = (tid < 64) ? src[ec] : dst[ec];
            }
        }

        // ---- B: consume tile tc (MFMA + epilogue; hides A's latency) ----
        if (do_c) {
            const int e0c = tc * 64;
            const unsigned char* Ab = A_lds[ci];
            #pragma unroll
            for (int et = 0; et < 4; ++et) {
                const int e_row = et * 16 + lr;
                short8 bfrag[4];
                #pragma unroll
                for (int ks = 0; ks < 4; ++ks) {
                    int off = (e_row * 256 + (ks * 32 + lg * 8) * 2) ^ ((e_row & 7) << 4);
                    bfrag[ks] = *(const short8*)(Ab + off);
                }
                f32x4 acc[2];
                acc[0] = (f32x4){0.f, 0.f, 0.f, 0.f};
                acc[1] = (f32x4){0.f, 0.f, 0.f, 0.f};
                #pragma unroll
                for (int ks = 0; ks < 4; ++ks)
                    #pragma unroll
                    for (int nt = 0; nt < 2; ++nt)
                        acc[nt] = __builtin_amdgcn_mfma_f32_16x16x32_bf16(
                            wfrag[nt][ks], bfrag[ks], acc[nt], 0, 0, 0);

                const int el = e_row;            // col = lane&15 = edge in tile
                const int e = e0c + el;
                const int zs = zs_s[ci][el], zd = zd_s[ci][el];
                #pragma unroll
                for (int nt = 0; nt < 2; ++nt) {
                    int n4 = w * 32 + nt * 16 + lg * 4;
                    const f32x4 p1 = *(const f32x4*)(P1 + zs * EMB + n4);
                    const f32x4 p2 = *(const f32x4*)(P2 + zd * EMB + n4);
                    f32x4 o;
                    o.x = silu_f(acc[nt][0] + p1.x + p2.x);
                    o.y = silu_f(acc[nt][1] + p1.y + p2.y);
                    o.z = silu_f(acc[nt][2] + p1.z + p2.z);
                    o.w = silu_f(acc[nt][3] + p1.w + p2.w);
                    if (e < E)
                        __builtin_nontemporal_store(
                            o, (f32x4*)(out_m + (size_t)e * EMB + n4));  // NT
                }
            }
        }

        if (do_p) {
            // ---- C: Z gather for produce tile (hidden under D) ----
            int zreg = 0;
            if (tid < 128) zreg = Z[iv];

            // ---- D: producer — weights via wave-uniform scalar loads ----
            // edge = lane; wave wu computes k in [32wu, 32wu+32)
            #pragma unroll
            for (int c = 0; c < 4; ++c) {
                const float* wp0 = Wrp + (size_t)(wu * 32 + c * 8) * 8;
                short8 pk;
                #pragma unroll
                for (int j = 0; j < 8; ++j) {
                    const float* wp = wp0 + j * 8;      // uniform -> s_load
                    float pre = wp[6] + ra.x * wp[0] + ra.y * wp[1] +
                                rb.x * wp[2] + rb.y * wp[3] +
                                rc.x * wp[4] + rc.y * wp[5];
                    pk[j] = bf16s(silu_f(pre));
                }
                int k0 = wu * 32 + c * 8;
                int off = (lane * 256 + k0 * 2) ^ ((lane & 7) << 4);
                *(short8*)(A_lds[pi] + off) = pk;
            }

            // ---- E: stash z indices for next iteration's consumer ----
            if (tid < 64) zs_s[pi][tid] = zreg;
            else if (tid < 128) zd_s[pi][tid - 64] = zreg;
        }

        lds_barrier();   // single barrier per tile; no vmcnt drain
    }
}

extern "C" void kernel_launch(void* const* d_in, const int* in_sizes, int n_in,
                              void* d_out, int out_size, void* d_ws, size_t ws_size,
                              hipStream_t stream) {
    const int* Z = (const int*)d_in[0];
    const int* src = (const int*)d_in[1];
    const int* dst = (const int*)d_in[2];
    const float* rbf = (const float*)d_in[3];
    const float* dvec = (const float*)d_in[4];
    const float* emb = (const float*)d_in[5];
    const float* Wr = (const float*)d_in[6];
    const float* brbf = (const float*)d_in[7];
    const float* Wd = (const float*)d_in[8];
    const float* bd = (const float*)d_in[9];

    const int N = in_sizes[0];
    const int E = in_sizes[1];

    float* out_h = (float*)d_out;
    float* out_m = out_h + (size_t)N * EMB;
    float* out_env = out_m + (size_t)E * EMB;

    // workspace: P1 | P2 (95*128 f32 each) | W3 bf16 (128*128) | Wrp (128*8 f32)
    float* P1 = (float*)d_ws;
    float* P2 = P1 + NTYPES * EMB;
    unsigned short* W3b = (unsigned short*)(P2 + NTYPES * EMB);
    float* Wrp = (float*)(W3b + EMB * EMB);

    prep_kernel<<<2 * NTYPES + 9, 128, 0, stream>>>(emb, Wd, bd, Wr, brbf,
                                                    P1, P2, W3b, Wrp);

    int hblocks = (N * (EMB / 4) + 255) / 256;
    h_kernel<<<hblocks, 256, 0, stream>>>(Z, emb, out_h, N);

    int eblocks = (E + 255) / 256;
    env_kernel<<<eblocks, 256, 0, stream>>>(dvec, out_env, E);

    int ntiles = (E + 63) / 64;
    int grid = ntiles < 1024 ? ntiles : 1024;
    edge_kernel<<<grid, 256, 0, stream>>>(Z, src, dst, rbf,
                                          P1, P2, W3b, Wrp,
                                          out_m, E, ntiles);
}

// Round 12
// 154.836 us; speedup vs baseline: 1.4355x; 1.0609x over previous
//
#include <hip/hip_runtime.h>
#include <hip/hip_bf16.h>
#include <math.h>

#define CUTOFFV 5.0f
#define NRAD 6
#define EMB 128
#define NTYPES 95
#define PI_F 3.14159265358979323846f

typedef short short8 __attribute__((ext_vector_type(8)));
typedef float f32x4 __attribute__((ext_vector_type(4)));
typedef float f32x2 __attribute__((ext_vector_type(2)));

__device__ __forceinline__ unsigned short f2bf(float f) {
    union { float f; unsigned int u; } v; v.f = f;
    unsigned int u = v.u;
    unsigned int r = (u + 0x7FFFu + ((u >> 16) & 1u)) >> 16;
    return (unsigned short)r;
}

// compiler-lowered bf16 convert (RTNE, emits HW cvt)
__device__ __forceinline__ short bf16s(float f) {
    union { __hip_bfloat16 h; short s; } u;
    u.h = __float2bfloat16(f);
    return u.s;
}

__device__ __forceinline__ float fast_rcp(float x) {
    float y;
    asm("v_rcp_f32 %0, %1" : "=v"(y) : "v"(x));
    return y;
}

// silu via hardware rcp (1 ulp) instead of precise-division sequence
__device__ __forceinline__ float silu_f(float x) {
    return x * fast_rcp(1.0f + __expf(-x));
}

// LDS-only barrier: waits ds ops (lgkmcnt) but does NOT drain vmcnt.
__device__ __forceinline__ void lds_barrier() {
    __builtin_amdgcn_sched_barrier(0);
    asm volatile("s_waitcnt lgkmcnt(0)\n\ts_barrier" ::: "memory");
    __builtin_amdgcn_sched_barrier(0);
}

// ---- prep: P1 = emb@W1^T + b_dense, P2 = emb@W2^T, W3 -> bf16, Wrp pack ----
__global__ void prep_kernel(const float* __restrict__ emb,
                            const float* __restrict__ Wd,
                            const float* __restrict__ bd,
                            const float* __restrict__ Wr,
                            const float* __restrict__ brbf,
                            float* __restrict__ P1, float* __restrict__ P2,
                            unsigned short* __restrict__ W3b,
                            float* __restrict__ Wrp) {
    int b = blockIdx.x, tid = threadIdx.x;
    if (b < 2 * NTYPES) {
        int t = b / NTYPES, z = b % NTYPES;
        __shared__ float emb_s[EMB];
        emb_s[tid] = emb[z * EMB + tid];
        __syncthreads();
        float acc = (t == 0) ? bd[tid] : 0.0f;
        const float* wrow = Wd + (size_t)tid * 384 + t * EMB;
        #pragma unroll 8
        for (int j = 0; j < EMB; ++j) acc += emb_s[j] * wrow[j];
        (t == 0 ? P1 : P2)[z * EMB + tid] = acc;
    } else if (b < 2 * NTYPES + 8) {
        int g = (b - 2 * NTYPES) * 128 + tid;   // 0..1023
        for (int i = g; i < EMB * EMB; i += 8 * 128) {
            int n = i >> 7, k = i & 127;
            W3b[i] = f2bf(Wd[(size_t)n * 384 + 256 + k]);
        }
    } else {
        // Wrp[k][8] = {w0..w5, bias, 0}
        if (tid < EMB) {
            int k = tid;
            #pragma unroll
            for (int j = 0; j < 6; ++j) Wrp[k * 8 + j] = Wr[k * 6 + j];
            Wrp[k * 8 + 6] = brbf[k];
            Wrp[k * 8 + 7] = 0.0f;
        }
    }
}

// ---------------- h output: gather rows of emb_table --------------------------
__global__ void h_kernel(const int* __restrict__ Z, const float* __restrict__ emb,
                         float* __restrict__ out_h, int N) {
    int idx = blockIdx.x * 256 + threadIdx.x;  // float4 index
    int total = N * (EMB / 4);
    if (idx >= total) return;
    int v = idx >> 5, c = idx & 31;            // 32 float4 per row
    int z = Z[v];
    const f32x4* e4 = (const f32x4*)emb;
    f32x4* o4 = (f32x4*)out_h;
    o4[idx] = e4[z * 32 + c];
}

// ---------------- env: pure streaming (sincos + Chebyshev), nt stores ---------
__global__ void env_kernel(const float* __restrict__ dvec,
                           float* __restrict__ out_env, int E) {
    int e = blockIdx.x * 256 + threadIdx.x;
    if (e >= E) return;
    float x = dvec[e] * (1.0f / CUTOFFV);   // (0,1]
    float inv = fast_rcp(x);
    float x2 = x * x;
    float x5 = x2 * x2 * x;
    float env = inv + x5 * (-28.0f + x * (48.0f - 21.0f * x));
    float s1, c1;
    __sincosf(PI_F * x, &s1, &c1);
    float twoc = 2.0f * c1;
    float f = env * inv;
    float s2 = twoc * s1;
    float s3 = twoc * s2 - s1;
    float s4 = twoc * s3 - s2;
    float s5 = twoc * s4 - s3;
    float s6 = twoc * s5 - s4;
    float* o = out_env + (size_t)e * 6;
    __builtin_nontemporal_store((f32x2){f * s1, f * s2}, (f32x2*)o);
    __builtin_nontemporal_store((f32x2){f * s3, f * s4}, (f32x2*)(o + 2));
    __builtin_nontemporal_store((f32x2){f * s5, f * s6}, (f32x2*)(o + 4));
}

// -- persistent edge kernel: dbuf pipeline, s_load producer, NT full-line ------
__global__ void __launch_bounds__(256, 4)
edge_kernel(const int* __restrict__ Z, const int* __restrict__ src,
            const int* __restrict__ dst, const float* __restrict__ rbf,
            const float* __restrict__ P1, const float* __restrict__ P2,
            const unsigned short* __restrict__ W3b,
            const float* __restrict__ Wrp,
            float* __restrict__ out_m,
            int E, int ntiles) {
    __shared__ unsigned char A_lds[2][64 * 256]; // bf16 [edge][k], swizzled
    __shared__ int zs_s[2][64], zd_s[2][64];

    const int tid = threadIdx.x;
    const int lane = tid & 63;
    const int w = tid >> 6;          // wave id
    const int lr = lane & 15;
    const int lg = lane >> 4;
    const int wu = __builtin_amdgcn_readfirstlane(w);  // wave-uniform wave id

    // ---- per-block loop-invariant: W3 fragments (wave w owns n-slice) ----
    short8 wfrag[2][4];
    #pragma unroll
    for (int nt = 0; nt < 2; ++nt) {
        int n = w * 32 + nt * 16 + lr;
        #pragma unroll
        for (int ks = 0; ks < 4; ++ks)
            wfrag[nt][ks] = *(const short8*)(W3b + n * EMB + ks * 32 + lg * 8);
    }

    for (int i = 0; ; ++i) {
        const int tp = blockIdx.x + i * gridDim.x;   // tile to produce
        const int tc = tp - gridDim.x;               // tile to consume (prev it)
        const bool do_p = (tp < ntiles);
        const bool do_c = (i > 0) && (tc < ntiles);
        if (!do_p && !do_c) break;
        const int pi = i & 1, ci = pi ^ 1;

        // ---- A: issue produce-tile global loads (consumed after B) ----
        f32x2 ra = {0.f, 0.f}, rb = {0.f, 0.f}, rc = {0.f, 0.f};
        int iv = 0;
        if (do_p) {
            const int e0p = tp * 64;
            int ecl = e0p + lane; if (ecl >= E) ecl = E - 1;
            const f32x2* r2 = (const f32x2*)(rbf + (size_t)ecl * 6);
            ra = r2[0]; rb = r2[1]; rc = r2[2];
            if (tid < 128) {                         // waves 0,1: src / dst
                int ec = e0p + (tid & 63); if (ec >= E) ec = E - 1;
                iv = (tid < 64) ? src[ec] : dst[ec];
            }
        }

        // ---- B: consume tile tc — MFMA + epilogue into REGISTERS ----
        f32x4 o[4][2];
        if (do_c) {
            const unsigned char* Ab = A_lds[ci];
            #pragma unroll
            for (int et = 0; et < 4; ++et) {
                const int e_row = et * 16 + lr;
                short8 bfrag[4];
                #pragma unroll
                for (int ks = 0; ks < 4; ++ks) {
                    int off = (e_row * 256 + (ks * 32 + lg * 8) * 2) ^ ((e_row & 7) << 4);
                    bfrag[ks] = *(const short8*)(Ab + off);
                }
                f32x4 acc[2];
                acc[0] = (f32x4){0.f, 0.f, 0.f, 0.f};
                acc[1] = (f32x4){0.f, 0.f, 0.f, 0.f};
                #pragma unroll
                for (int ks = 0; ks < 4; ++ks)
                    #pragma unroll
                    for (int nt = 0; nt < 2; ++nt)
                        acc[nt] = __builtin_amdgcn_mfma_f32_16x16x32_bf16(
                            wfrag[nt][ks], bfrag[ks], acc[nt], 0, 0, 0);

                const int el = e_row;            // col = lane&15 = edge in tile
                const int zs = zs_s[ci][el], zd = zd_s[ci][el];
                #pragma unroll
                for (int nt = 0; nt < 2; ++nt) {
                    int n4 = w * 32 + nt * 16 + lg * 4;
                    const f32x4 p1 = *(const f32x4*)(P1 + zs * EMB + n4);
                    const f32x4 p2 = *(const f32x4*)(P2 + zd * EMB + n4);
                    f32x4 v;
                    v.x = silu_f(acc[nt][0] + p1.x + p2.x);
                    v.y = silu_f(acc[nt][1] + p1.y + p2.y);
                    v.z = silu_f(acc[nt][2] + p1.z + p2.z);
                    v.w = silu_f(acc[nt][3] + p1.w + p2.w);
                    o[et][nt] = v;
                }
            }
        }

        if (do_p) {
            // ---- C: Z gather for produce tile (hidden under D) ----
            int zreg = 0;
            if (tid < 128) zreg = Z[iv];

            // ---- D: producer — weights via wave-uniform scalar loads ----
            #pragma unroll
            for (int c = 0; c < 4; ++c) {
                const float* wp0 = Wrp + (size_t)(wu * 32 + c * 8) * 8;
                short8 pk;
                #pragma unroll
                for (int j = 0; j < 8; ++j) {
                    const float* wp = wp0 + j * 8;      // uniform -> s_load
                    float pre = wp[6] + ra.x * wp[0] + ra.y * wp[1] +
                                rb.x * wp[2] + rb.y * wp[3] +
                                rc.x * wp[4] + rc.y * wp[5];
                    pk[j] = bf16s(silu_f(pre));
                }
                int k0 = wu * 32 + c * 8;
                int off = (lane * 256 + k0 * 2) ^ ((lane & 7) << 4);
                *(short8*)(A_lds[pi] + off) = pk;
            }

            // ---- E: stash z indices for next iteration's consumer ----
            if (tid < 64) zs_s[pi][tid] = zreg;
            else if (tid < 128) zd_s[pi][tid - 64] = zreg;
        }

        lds_barrier();   // #1: producer visible; A_lds[ci] reads complete

        // ---- F: staged epilogue store — reuse A_lds[ci] as f32 transpose
        //        buffer (16 KB = 32 edges x 512 B); two passes of 32 edges.
        //        Result: lane-consecutive NT stores, 8 full 128B lines / wave.
        if (do_c) {
            const int e0c = tc * 64;
            unsigned char* Sb = (unsigned char*)A_lds[ci];
            #pragma unroll
            for (int p = 0; p < 2; ++p) {
                // write: o[2p+q][nt] -> row epass=q*16+lr, swizzled
                #pragma unroll
                for (int q = 0; q < 2; ++q) {
                    const int epass = q * 16 + lr;
                    const int swz = (lr & 7) << 4;
                    #pragma unroll
                    for (int nt = 0; nt < 2; ++nt) {
                        int addr = epass * 512 + ((w * 128 + nt * 64 + lg * 16) ^ swz);
                        *(f32x4*)(Sb + addr) = o[2 * p + q][nt];
                    }
                }
                lds_barrier();   // writes visible
                // read linear + full-line NT store
                #pragma unroll
                for (int s = 0; s < 4; ++s) {
                    const int epass = s * 8 + (tid >> 5);
                    const int within = (tid & 31) * 16;
                    const int rd = epass * 512 + (within ^ ((epass & 7) << 4));
                    f32x4 v = *(const f32x4*)(Sb + rd);
                    const int ge = e0c + p * 32 + epass;
                    if (ge < E)
                        __builtin_nontemporal_store(
                            v, (f32x4*)(out_m + (size_t)ge * EMB + (tid & 31) * 4));
                }
                lds_barrier();   // reads done before buffer reuse
            }
        }
    }
}

extern "C" void kernel_launch(void* const* d_in, const int* in_sizes, int n_in,
                              void* d_out, int out_size, void* d_ws, size_t ws_size,
                              hipStream_t stream) {
    const int* Z = (const int*)d_in[0];
    const int* src = (const int*)d_in[1];
    const int* dst = (const int*)d_in[2];
    const float* rbf = (const float*)d_in[3];
    const float* dvec = (const float*)d_in[4];
    const float* emb = (const float*)d_in[5];
    const float* Wr = (const float*)d_in[6];
    const float* brbf = (const float*)d_in[7];
    const float* Wd = (const float*)d_in[8];
    const float* bd = (const float*)d_in[9];

    const int N = in_sizes[0];
    const int E = in_sizes[1];

    float* out_h = (float*)d_out;
    float* out_m = out_h + (size_t)N * EMB;
    float* out_env = out_m + (size_t)E * EMB;

    // workspace: P1 | P2 (95*128 f32 each) | W3 bf16 (128*128) | Wrp (128*8 f32)
    float* P1 = (float*)d_ws;
    float* P2 = P1 + NTYPES * EMB;
    unsigned short* W3b = (unsigned short*)(P2 + NTYPES * EMB);
    float* Wrp = (float*)(W3b + EMB * EMB);

    prep_kernel<<<2 * NTYPES + 9, 128, 0, stream>>>(emb, Wd, bd, Wr, brbf,
                                                    P1, P2, W3b, Wrp);

    int hblocks = (N * (EMB / 4) + 255) / 256;
    h_kernel<<<hblocks, 256, 0, stream>>>(Z, emb, out_h, N);

    int eblocks = (E + 255) / 256;
    env_kernel<<<eblocks, 256, 0, stream>>>(dvec, out_env, E);

    int ntiles = (E + 63) / 64;
    int grid = ntiles < 1024 ? ntiles : 1024;
    edge_kernel<<<grid, 256, 0, stream>>>(Z, src, dst, rbf,
                                          P1, P2, W3b, Wrp,
                                          out_m, E, ntiles);
}

// Round 13
// 154.234 us; speedup vs baseline: 1.4411x; 1.0039x over previous
//
#include <hip/hip_runtime.h>
#include <hip/hip_bf16.h>
#include <math.h>

#define CUTOFFV 5.0f
#define NRAD 6
#define EMB 128
#define NTYPES 95
#define PI_F 3.14159265358979323846f

typedef short short8 __attribute__((ext_vector_type(8)));
typedef float f32x4 __attribute__((ext_vector_type(4)));
typedef float f32x2 __attribute__((ext_vector_type(2)));

__device__ __forceinline__ unsigned short f2bf(float f) {
    union { float f; unsigned int u; } v; v.f = f;
    unsigned int u = v.u;
    unsigned int r = (u + 0x7FFFu + ((u >> 16) & 1u)) >> 16;
    return (unsigned short)r;
}

// compiler-lowered bf16 convert (RTNE, emits HW cvt)
__device__ __forceinline__ short bf16s(float f) {
    union { __hip_bfloat16 h; short s; } u;
    u.h = __float2bfloat16(f);
    return u.s;
}

__device__ __forceinline__ float fast_rcp(float x) {
    float y;
    asm("v_rcp_f32 %0, %1" : "=v"(y) : "v"(x));
    return y;
}

// silu via hardware rcp (1 ulp) instead of precise-division sequence
__device__ __forceinline__ float silu_f(float x) {
    return x * fast_rcp(1.0f + __expf(-x));
}

// LDS-only barrier: waits ds ops (lgkmcnt) but does NOT drain vmcnt.
__device__ __forceinline__ void lds_barrier() {
    __builtin_amdgcn_sched_barrier(0);
    asm volatile("s_waitcnt lgkmcnt(0)\n\ts_barrier" ::: "memory");
    __builtin_amdgcn_sched_barrier(0);
}

// ---- prep: P1 = emb@W1^T + b_dense, P2 = emb@W2^T, W3 -> bf16, Wrp pack ----
__global__ void prep_kernel(const float* __restrict__ emb,
                            const float* __restrict__ Wd,
                            const float* __restrict__ bd,
                            const float* __restrict__ Wr,
                            const float* __restrict__ brbf,
                            float* __restrict__ P1, float* __restrict__ P2,
                            unsigned short* __restrict__ W3b,
                            float* __restrict__ Wrp) {
    int b = blockIdx.x, tid = threadIdx.x;
    if (b < 2 * NTYPES) {
        int t = b / NTYPES, z = b % NTYPES;
        __shared__ float emb_s[EMB];
        emb_s[tid] = emb[z * EMB + tid];
        __syncthreads();
        float acc = (t == 0) ? bd[tid] : 0.0f;
        const float* wrow = Wd + (size_t)tid * 384 + t * EMB;
        #pragma unroll 8
        for (int j = 0; j < EMB; ++j) acc += emb_s[j] * wrow[j];
        (t == 0 ? P1 : P2)[z * EMB + tid] = acc;
    } else if (b < 2 * NTYPES + 8) {
        int g = (b - 2 * NTYPES) * 128 + tid;   // 0..1023
        for (int i = g; i < EMB * EMB; i += 8 * 128) {
            int n = i >> 7, k = i & 127;
            W3b[i] = f2bf(Wd[(size_t)n * 384 + 256 + k]);
        }
    } else {
        // Wrp[k][8] = {w0..w5, bias, 0}
        if (tid < EMB) {
            int k = tid;
            #pragma unroll
            for (int j = 0; j < 6; ++j) Wrp[k * 8 + j] = Wr[k * 6 + j];
            Wrp[k * 8 + 6] = brbf[k];
            Wrp[k * 8 + 7] = 0.0f;
        }
    }
}

// -- persistent edge kernel: fused h/env prologue + dbuf pipeline tiles --------
__global__ void __launch_bounds__(256, 4)
edge_kernel(const int* __restrict__ Z, const int* __restrict__ src,
            const int* __restrict__ dst, const float* __restrict__ rbf,
            const float* __restrict__ dvec, const float* __restrict__ emb,
            const float* __restrict__ P1, const float* __restrict__ P2,
            const unsigned short* __restrict__ W3b,
            const float* __restrict__ Wrp,
            float* __restrict__ out_h, float* __restrict__ out_m,
            float* __restrict__ out_env,
            int N, int E, int ntiles) {
    __shared__ unsigned char A_lds[2][64 * 256]; // bf16 [edge][k], swizzled
    __shared__ int zs_s[2][64], zd_s[2][64];

    const int tid = threadIdx.x;
    const int lane = tid & 63;
    const int w = tid >> 6;          // wave id
    const int lr = lane & 15;
    const int lg = lane >> 4;
    const int wu = __builtin_amdgcn_readfirstlane(w);  // wave-uniform wave id

    // ---- fused h output: grid-stride gather of emb rows (nt full lines) ----
    {
        const int total_h = N * (EMB / 4);
        const f32x4* e4 = (const f32x4*)emb;
        for (int idx = blockIdx.x * 256 + tid; idx < total_h;
             idx += gridDim.x * 256) {
            int v = idx >> 5, c = idx & 31;
            __builtin_nontemporal_store(e4[Z[v] * 32 + c], (f32x4*)out_h + idx);
        }
    }
    // ---- fused env output: grid-stride sincos + Chebyshev (nt stores) ----
    for (int e = blockIdx.x * 256 + tid; e < E; e += gridDim.x * 256) {
        float x = dvec[e] * (1.0f / CUTOFFV);   // (0,1]
        float inv = fast_rcp(x);
        float x2 = x * x;
        float x5 = x2 * x2 * x;
        float env = inv + x5 * (-28.0f + x * (48.0f - 21.0f * x));
        float s1, c1;
        __sincosf(PI_F * x, &s1, &c1);
        float twoc = 2.0f * c1;
        float f = env * inv;
        float s2 = twoc * s1;
        float s3 = twoc * s2 - s1;
        float s4 = twoc * s3 - s2;
        float s5 = twoc * s4 - s3;
        float s6 = twoc * s5 - s4;
        float* o = out_env + (size_t)e * 6;
        __builtin_nontemporal_store((f32x2){f * s1, f * s2}, (f32x2*)o);
        __builtin_nontemporal_store((f32x2){f * s3, f * s4}, (f32x2*)(o + 2));
        __builtin_nontemporal_store((f32x2){f * s5, f * s6}, (f32x2*)(o + 4));
    }

    // ---- per-block loop-invariant: W3 fragments (wave w owns n-slice) ----
    short8 wfrag[2][4];
    #pragma unroll
    for (int nt = 0; nt < 2; ++nt) {
        int n = w * 32 + nt * 16 + lr;
        #pragma unroll
        for (int ks = 0; ks < 4; ++ks)
            wfrag[nt][ks] = *(const short8*)(W3b + n * EMB + ks * 32 + lg * 8);
    }

    for (int i = 0; ; ++i) {
        const int tp = blockIdx.x + i * gridDim.x;   // tile to produce
        const int tc = tp - gridDim.x;               // tile to consume (prev it)
        const bool do_p = (tp < ntiles);
        const bool do_c = (i > 0) && (tc < ntiles);
        if (!do_p && !do_c) break;
        const int pi = i & 1, ci = pi ^ 1;

        // ---- A: issue produce-tile global loads (consumed after B) ----
        f32x2 ra = {0.f, 0.f}, rb = {0.f, 0.f}, rc = {0.f, 0.f};
        int iv = 0;
        if (do_p) {
            const int e0p = tp * 64;
            int ecl = e0p + lane; if (ecl >= E) ecl = E - 1;
            const f32x2* r2 = (const f32x2*)(rbf + (size_t)ecl * 6);
            ra = r2[0]; rb = r2[1]; rc = r2[2];
            if (tid < 128) {                         // waves 0,1: src / dst
                int ec = e0p + (tid & 63); if (ec >= E) ec = E - 1;
                iv = (tid < 64) ? src[ec] : dst[ec];
            }
        }

        // ---- B: consume tile tc — MFMA + epilogue into REGISTERS ----
        f32x4 o[4][2];
        if (do_c) {
            const unsigned char* Ab = A_lds[ci];
            #pragma unroll
            for (int et = 0; et < 4; ++et) {
                const int e_row = et * 16 + lr;
                short8 bfrag[4];
                #pragma unroll
                for (int ks = 0; ks < 4; ++ks) {
                    int off = (e_row * 256 + (ks * 32 + lg * 8) * 2) ^ ((e_row & 7) << 4);
                    bfrag[ks] = *(const short8*)(Ab + off);
                }
                f32x4 acc[2];
                acc[0] = (f32x4){0.f, 0.f, 0.f, 0.f};
                acc[1] = (f32x4){0.f, 0.f, 0.f, 0.f};
                #pragma unroll
                for (int ks = 0; ks < 4; ++ks)
                    #pragma unroll
                    for (int nt = 0; nt < 2; ++nt)
                        acc[nt] = __builtin_amdgcn_mfma_f32_16x16x32_bf16(
                            wfrag[nt][ks], bfrag[ks], acc[nt], 0, 0, 0);

                const int el = e_row;            // col = lane&15 = edge in tile
                const int zs = zs_s[ci][el], zd = zd_s[ci][el];
                #pragma unroll
                for (int nt = 0; nt < 2; ++nt) {
                    int n4 = w * 32 + nt * 16 + lg * 4;
                    const f32x4 p1 = *(const f32x4*)(P1 + zs * EMB + n4);
                    const f32x4 p2 = *(const f32x4*)(P2 + zd * EMB + n4);
                    f32x4 v;
                    v.x = silu_f(acc[nt][0] + p1.x + p2.x);
                    v.y = silu_f(acc[nt][1] + p1.y + p2.y);
                    v.z = silu_f(acc[nt][2] + p1.z + p2.z);
                    v.w = silu_f(acc[nt][3] + p1.w + p2.w);
                    o[et][nt] = v;
                }
            }
        }

        if (do_p) {
            // ---- C: Z gather for produce tile (hidden under D) ----
            int zreg = 0;
            if (tid < 128) zreg = Z[iv];

            // ---- D: producer — weights via wave-uniform scalar loads ----
            #pragma unroll
            for (int c = 0; c < 4; ++c) {
                const float* wp0 = Wrp + (size_t)(wu * 32 + c * 8) * 8;
                short8 pk;
                #pragma unroll
                for (int j = 0; j < 8; ++j) {
                    const float* wp = wp0 + j * 8;      // uniform -> s_load
                    float pre = wp[6] + ra.x * wp[0] + ra.y * wp[1] +
                                rb.x * wp[2] + rb.y * wp[3] +
                                rc.x * wp[4] + rc.y * wp[5];
                    pk[j] = bf16s(silu_f(pre));
                }
                int k0 = wu * 32 + c * 8;
                int off = (lane * 256 + k0 * 2) ^ ((lane & 7) << 4);
                *(short8*)(A_lds[pi] + off) = pk;
            }

            // ---- E: stash z indices for next iteration's consumer ----
            if (tid < 64) zs_s[pi][tid] = zreg;
            else if (tid < 128) zd_s[pi][tid - 64] = zreg;
        }

        lds_barrier();   // #1: producer visible; A_lds[ci] reads complete

        // ---- F: staged epilogue store — reuse A_lds[ci] as f32 transpose
        //        buffer (16 KB = 32 edges x 512 B); two passes of 32 edges.
        //        Result: lane-consecutive NT stores, 8 full 128B lines / wave.
        if (do_c) {
            const int e0c = tc * 64;
            unsigned char* Sb = (unsigned char*)A_lds[ci];
            #pragma unroll
            for (int p = 0; p < 2; ++p) {
                // write: o[2p+q][nt] -> row epass=q*16+lr, swizzled
                #pragma unroll
                for (int q = 0; q < 2; ++q) {
                    const int epass = q * 16 + lr;
                    const int swz = (lr & 7) << 4;
                    #pragma unroll
                    for (int nt = 0; nt < 2; ++nt) {
                        int addr = epass * 512 + ((w * 128 + nt * 64 + lg * 16) ^ swz);
                        *(f32x4*)(Sb + addr) = o[2 * p + q][nt];
                    }
                }
                lds_barrier();   // writes visible
                // read linear + full-line NT store
                #pragma unroll
                for (int s = 0; s < 4; ++s) {
                    const int epass = s * 8 + (tid >> 5);
                    const int within = (tid & 31) * 16;
                    const int rd = epass * 512 + (within ^ ((epass & 7) << 4));
                    f32x4 v = *(const f32x4*)(Sb + rd);
                    const int ge = e0c + p * 32 + epass;
                    if (ge < E)
                        __builtin_nontemporal_store(
                            v, (f32x4*)(out_m + (size_t)ge * EMB + (tid & 31) * 4));
                }
                lds_barrier();   // reads done before buffer reuse
            }
        }
    }
}

extern "C" void kernel_launch(void* const* d_in, const int* in_sizes, int n_in,
                              void* d_out, int out_size, void* d_ws, size_t ws_size,
                              hipStream_t stream) {
    const int* Z = (const int*)d_in[0];
    const int* src = (const int*)d_in[1];
    const int* dst = (const int*)d_in[2];
    const float* rbf = (const float*)d_in[3];
    const float* dvec = (const float*)d_in[4];
    const float* emb = (const float*)d_in[5];
    const float* Wr = (const float*)d_in[6];
    const float* brbf = (const float*)d_in[7];
    const float* Wd = (const float*)d_in[8];
    const float* bd = (const float*)d_in[9];

    const int N = in_sizes[0];
    const int E = in_sizes[1];

    float* out_h = (float*)d_out;
    float* out_m = out_h + (size_t)N * EMB;
    float* out_env = out_m + (size_t)E * EMB;

    // workspace: P1 | P2 (95*128 f32 each) | W3 bf16 (128*128) | Wrp (128*8 f32)
    float* P1 = (float*)d_ws;
    float* P2 = P1 + NTYPES * EMB;
    unsigned short* W3b = (unsigned short*)(P2 + NTYPES * EMB);
    float* Wrp = (float*)(W3b + EMB * EMB);

    prep_kernel<<<2 * NTYPES + 9, 128, 0, stream>>>(emb, Wd, bd, Wr, brbf,
                                                    P1, P2, W3b, Wrp);

    int ntiles = (E + 63) / 64;
    int grid = ntiles < 1024 ? ntiles : 1024;
    edge_kernel<<<grid, 256, 0, stream>>>(Z, src, dst, rbf, dvec, emb,
                                          P1, P2, W3b, Wrp,
                                          out_h, out_m, out_env,
                                          N, E, ntiles);
}